// Round 12
// baseline (96.951 us; speedup 1.0000x reference)
//
#include <hip/hip_runtime.h>
#include <math.h>

#define NPART 4096
#define NBLK  512
#define NTHR  256
#define IPB   8     // particles (i) per block
#define SMAX  512   // max local collision-set size (expected ~70)
#define GDIM  64    // grid cells per axis
#define NCELL (GDIM * GDIM)

// Constants, rounded exactly as the reference's weak-typed doubles -> f32
constexpr float RORC   = (float)(2.5e-5 + 3.15e-6);    // RO + RC
constexpr float RORC2  = RORC * RORC;
constexpr float RRF    = 8e-6f;                        // RR
constexpr float RR2    = RRF * RRF;
constexpr float TWORC  = (float)(2.0 * 3.15e-6);       // 2*RC
constexpr float TWORC2 = TWORC * TWORC;
constexpr float C21RC  = (float)(2.1 * 3.15e-6);       // 2.1*RC
constexpr float RCAND2 = 1.6e-9f;                      // (4e-5)^2 >= 3-hop chain span
constexpr float GMIN   = -2.048e-3f;                   // grid origin
constexpr float GINV   = 15625.0f;                     // 1 / 6.4e-5 (cell size)
constexpr float C_ROT  = (float)(0.2 * 25.0 * 0.0028); // dt*Gamma*DR
constexpr float C_RN1  = (float)0.07483314773547883;   // f32(sqrt(2*DR))
constexpr float C_SQDT = (float)0.4472135954999579;    // f32(sqrt(dt))
constexpr float C_TRV  = (float)(0.2 * 5e-7);          // dt*velocity
constexpr float C_HALF = (float)0.7071067811865476;    // f32(sqrt(0.5))
constexpr float C_SQ2T = (float)1.6733200530681511e-07;// f32(sqrt(2*DT_TRANS))
constexpr float EPSF   = 1e-14f;

__device__ __forceinline__ int cell_of(float x, float y) {
    int cx = (int)floorf((x - GMIN) * GINV);
    int cy = (int)floorf((y - GMIN) * GINV);
    cx = min(max(cx, 0), GDIM - 1);
    cy = min(max(cy, 0), GDIM - 1);
    return cy * GDIM + cx;
}

// ---------------------------------------------------------------------------
// ONE kernel, 512 blocks x 256 thr, block-local. vs R11: the O(N^2/512)
// LDS scan (latency-bound ~30us in every variant) is replaced by a per-block
// 64x64 counting-sort grid: histogram -> 4096-cell scan -> scatter, then each
// own-i sweeps only its 3x3 neighborhood (cell 6.4e-5 > all radii 4e-5;
// clamping is monotone so edge cells stay correct). n_r/S/Ro sums become
// register partials + deterministic LDS reduce. D1/D2/mean/epilogue = R11.
// ---------------------------------------------------------------------------
__global__ __launch_bounds__(NTHR) void fused_all(
        const float2* __restrict__ pos, const float2* __restrict__ ori,
        const float* __restrict__ Deltas, const float* __restrict__ rot_noise,
        const float2* __restrict__ trans_noise, float2* __restrict__ out) {
    __shared__ float4   pp4[NPART / 2];     // 32 KB positions (float2[NPART])
    __shared__ int      ptr[NCELL];         // 16 KB cell counts->starts->ends
    __shared__ unsigned short sortid[NPART];// 8 KB  cell-sorted particle ids
    __shared__ float    sred[5 * NTHR];     // 5 KB  partials / scan / mean
    __shared__ float    res[5][IPB];        // n_r, Sx, Sy, Ox, Oy per own-i
    __shared__ unsigned bmap[NPART / 32];   // 512 B candidate-set bitmap
    __shared__ int      Sidx[SMAX];         // 2 KB
    __shared__ float4   posS4[SMAX / 2];    // 4 KB collision-set positions
    __shared__ int      scnt;
    __shared__ int      iloc[IPB];
    float2* ppos_s = (float2*)pp4;
    float2* posS   = (float2*)posS4;
    int*    sredi  = (int*)sred;

    const int tid  = threadIdx.x;
    const int il   = tid >> 5;            // own-i index 0..7
    const int lane = tid & 31;
    const int gi   = blockIdx.x * IPB + il;
    if (tid == 0) scnt = 0;
    if (tid < NPART / 32) bmap[tid] = 0u;

    // ---- stage positions + zero cell table ----
    for (int k = 0; k < NPART / NTHR; ++k)
        ppos_s[k * NTHR + tid] = pos[k * NTHR + tid];
    for (int k = 0; k < NCELL / NTHR; ++k)
        ptr[k * NTHR + tid] = 0;
    __syncthreads();

    // ---- G1. histogram ----
    for (int k = 0; k < NPART / NTHR; ++k) {
        const int p = k * NTHR + tid;
        const float2 pp = ppos_s[p];
        atomicAdd(&ptr[cell_of(pp.x, pp.y)], 1);
    }
    __syncthreads();

    // ---- G2. exclusive scan of 4096 counts (16/thread + 256-scan) ----
    {
        const int base = tid * (NCELL / NTHR);
        int v[NCELL / NTHR];
        int sum = 0;
        #pragma unroll
        for (int t = 0; t < NCELL / NTHR; ++t) { v[t] = ptr[base + t]; sum += v[t]; }
        sredi[tid] = sum;
        __syncthreads();
        for (int off = 1; off < NTHR; off <<= 1) {
            const int a = (tid >= off) ? sredi[tid - off] : 0;
            __syncthreads();
            sredi[tid] += a;
            __syncthreads();
        }
        int run = sredi[tid] - sum;       // exclusive base of this chunk
        #pragma unroll
        for (int t = 0; t < NCELL / NTHR; ++t) { ptr[base + t] = run; run += v[t]; }
    }
    __syncthreads();

    // ---- G3. scatter (ptr becomes END offsets; begin[c] = ptr[c-1]) ----
    for (int k = 0; k < NPART / NTHR; ++k) {
        const int p = k * NTHR + tid;
        const float2 pp = ppos_s[p];
        const int slot = atomicAdd(&ptr[cell_of(pp.x, pp.y)], 1);
        sortid[slot] = (unsigned short)p;
    }
    __syncthreads();

    // ---- A. per-own-i 3x3 neighborhood sweep (32 lanes per i) ----
    const float2 pi = ppos_s[gi];
    {
        int cxi = (int)floorf((pi.x - GMIN) * GINV);
        int cyi = (int)floorf((pi.y - GMIN) * GINV);
        cxi = min(max(cxi, 0), GDIM - 1);
        cyi = min(max(cyi, 0), GDIM - 1);
        float nr = 0.f, sx = 0.f, sy = 0.f, oxs = 0.f, oys = 0.f;
        for (int dy = -1; dy <= 1; ++dy) {
            const int cy = cyi + dy;
            if (cy < 0 || cy >= GDIM) continue;
            for (int dx = -1; dx <= 1; ++dx) {
                const int cx = cxi + dx;
                if (cx < 0 || cx >= GDIM) continue;
                const int c  = cy * GDIM + cx;
                const int b0 = (c > 0) ? ptr[c - 1] : 0;
                const int e0 = ptr[c];
                for (int t = b0 + lane; t < e0; t += 32) {
                    const int j = sortid[t];
                    const float2 pj = ppos_s[j];
                    const float dxp = pj.x - pi.x, dyp = pj.y - pi.y;
                    const float r2 = fmaf(dxp, dxp, dyp * dyp);
                    if (r2 <= RCAND2) {   // incl. diagonal (sets own bit)
                        atomicOr(&bmap[j >> 5], 1u << (j & 31));
                        if (r2 <= RORC2) {            // inside_Ro
                            const float2 uj = ori[j]; // L2/L3-resident
                            oxs += uj.x; oys += uj.y;
                            if (r2 <= RR2 && r2 > 0.f) {
                                // in_front fails <=> dot<=0 && cross>=0
                                const float dt_ = fmaf(dxp, uj.x, dyp * uj.y);
                                const float cr_ = fmaf(dyp, uj.x, -dxp * uj.y);
                                if (!((dt_ <= 0.f) && (cr_ >= 0.f))) {
                                    nr += 1.f; sx += pj.x; sy += pj.y;
                                }
                            }
                        }
                    }
                }
            }
        }
        sred[0 * NTHR + il * 32 + lane] = nr;
        sred[1 * NTHR + il * 32 + lane] = sx;
        sred[2 * NTHR + il * 32 + lane] = sy;
        sred[3 * NTHR + il * 32 + lane] = oxs;
        sred[4 * NTHR + il * 32 + lane] = oys;
    }
    __syncthreads();

    // ---- B. res reduce (tid<40) + S-compaction from bmap (tid>=128) ----
    if (tid < 5 * IPB) {
        const int q = tid / IPB, ii = tid & (IPB - 1);
        float acc = 0.f;
        #pragma unroll
        for (int s = 0; s < 32; ++s) acc += sred[q * NTHR + ii * 32 + s];
        res[q][ii] = acc;
    } else if (tid >= 128 && tid < 128 + NPART / 32) {
        const int w = tid - 128;
        unsigned bits = bmap[w];
        while (bits) {
            const int b = __ffs(bits) - 1;
            bits &= bits - 1;
            const int p = w * 32 + b;
            const int slot = atomicAdd(&scnt, 1);
            if (slot < SMAX) {
                Sidx[slot] = p;
                if ((p >> 3) == (int)blockIdx.x) iloc[p & (IPB - 1)] = slot;
            }
        }
    }
    __syncthreads();
    const int nS = (scnt < SMAX) ? scnt : SMAX;

    // ---- D1. translate S members (reference-exact expression) ----
    for (int m = tid; m < nS; m += NTHR) {
        const int p = Sidx[m];
        const float2 pp = ppos_s[p];
        const float2 uu = ori[p];
        const float2 tn = trans_noise[p];
        posS[m] = make_float2(
            pp.x + (C_TRV * uu.x + ((tn.x * C_HALF) * C_SQ2T) * C_SQDT),
            pp.y + (C_TRV * uu.y + ((tn.y * C_HALF) * C_SQ2T) * C_SQDT));
    }

    // ---- C. mean of all positions (n_a == N) ----
    float mx = 0.f, my = 0.f;
    for (int k = 0; k < NPART / NTHR; ++k) {
        const float2 v = ppos_s[k * NTHR + tid];
        mx += v.x; my += v.y;
    }
    __syncthreads();                      // res-reduce reads of sred done
    sred[tid] = mx; sred[NTHR + tid] = my;
    __syncthreads();
    for (int s = NTHR / 2; s > 0; s >>= 1) {
        if (tid < s) { sred[tid] += sred[tid + s]; sred[NTHR + tid] += sred[NTHR + tid + s]; }
        __syncthreads();
    }
    const float cmx = sred[0]    * (1.f / NPART);
    const float cmy = sred[NTHR] * (1.f / NPART);

    // ---- C2. per-i epilogue (8 threads; sections 1..4) ----
    if (tid < IPB) {
        const int g2 = blockIdx.x * IPB + tid;
        const float2 p = ppos_s[g2];
        const float2 u = ori[g2];
        const float nrv = res[0][tid], sxv = res[1][tid], syv = res[2][tid];
        const float osx = res[3][tid], osy = res[4][tid];

        const float inv = 1.f / fmaxf(nrv, 1.f);
        const float sg  = (nrv > 0.f) ? 1.f : 0.f;
        const float Sx = sxv * inv - p.x * sg;
        const float Sy = syv * inv - p.y * sg;
        const float dxv = -Sx, dyv = -Sy;        // d = -S

        const float Psx = cmx - p.x;
        const float Psy = cmy - p.y;

        float sd, cd;
        sincosf(Deltas[0], &sd, &cd);
        const float Lx = Psx * cd - Psy * sd;    // Ps * exp(+i*Delta)
        const float Ly = Psx * sd + Psy * cd;
        const float Rx = Psx * cd + Psy * sd;    // Ps * exp(-i*Delta)
        const float Ry = Psy * cd - Psx * sd;

        const float no  = fmaxf(sqrtf(osx * osx + osy * osy + 1e-30f), EPSF);
        const float nl  = fmaxf(sqrtf(Lx * Lx + Ly * Ly + 1e-30f), EPSF);
        const float nrr = fmaxf(sqrtf(Rx * Rx + Ry * Ry + 1e-30f), EPSF);
        const float csl = (Lx * osx + Ly * osy) / (nl * no);
        const float csr = (Rx * osx + Ry * osy) / (nrr * no);
        const bool left = (csl >= csr);
        const float bx = left ? Lx : Rx;
        const float by = left ? Ly : Ry;

        float cx, cy;
        if (dxv != 0.f || dyv != 0.f)    { cx = dxv; cy = dyv; }
        else if (bx != 0.f || by != 0.f) { cx = bx;  cy = by;  }
        else                             { cx = 1.f; cy = 0.f; }

        const float dt_ = cx * u.x + cy * u.y;
        const float cr_ = cy * u.x - cx * u.y;
        const float sin_t = cr_ / sqrtf(dt_ * dt_ + cr_ * cr_);

        const float ang = C_ROT * sin_t + (rot_noise[g2] * C_RN1) * C_SQDT;
        float sa, ca;
        sincosf(ang, &sa, &ca);
        out[1 * NPART + g2] = make_float2(u.x * ca - u.y * sa,
                                          u.x * sa + u.y * ca);
        out[2 * NPART + g2] = make_float2(osx, osy);
        out[3 * NPART + g2] = make_float2(Lx, Ly);
        out[4 * NPART + g2] = make_float2(Rx, Ry);
    }
    __syncthreads();                      // posS complete

    // ---- D2. three local JACOBI passes over S, b-loop unrolled x4 ----
    for (int pass = 0; pass < 3; ++pass) {
        float px[2], py[2], ax[2] = {0.f, 0.f}, ay[2] = {0.f, 0.f};
        bool  mv[2];
        #pragma unroll
        for (int q = 0; q < 2; ++q) {
            const int m = tid + q * NTHR;
            mv[q] = (m < nS);
            if (mv[q]) { px[q] = posS[m].x; py[q] = posS[m].y; }
        }
        int b = 0;
        for (; b + 4 <= nS; b += 4) {
            const float4 w0 = posS4[(b >> 1)];     // entries b, b+1
            const float4 w1 = posS4[(b >> 1) + 1]; // entries b+2, b+3
            const float bxs[4] = {w0.x, w0.z, w1.x, w1.z};
            const float bys[4] = {w0.y, w0.w, w1.y, w1.w};
            #pragma unroll
            for (int s = 0; s < 4; ++s) {
                #pragma unroll
                for (int q = 0; q < 2; ++q) {
                    if (mv[q]) {
                        const float dx = bxs[s] - px[q], dy = bys[s] - py[q];
                        const float r2 = fmaf(dx, dx, dy * dy);
                        if (r2 <= TWORC2 && r2 > 0.f) {
                            const float ab = sqrtf(r2);
                            const float sc = (C21RC - ab) * 0.5f / ab;
                            ax[q] = fmaf(dx, sc, ax[q]);
                            ay[q] = fmaf(dy, sc, ay[q]);
                        }
                    }
                }
            }
        }
        for (; b < nS; ++b) {             // tail
            const float2 pb = posS[b];
            #pragma unroll
            for (int q = 0; q < 2; ++q) {
                if (mv[q]) {
                    const float dx = pb.x - px[q], dy = pb.y - py[q];
                    const float r2 = fmaf(dx, dx, dy * dy);
                    if (r2 <= TWORC2 && r2 > 0.f) {
                        const float ab = sqrtf(r2);
                        const float sc = (C21RC - ab) * 0.5f / ab;
                        ax[q] = fmaf(dx, sc, ax[q]);
                        ay[q] = fmaf(dy, sc, ay[q]);
                    }
                }
            }
        }
        __syncthreads();                  // all reads done (Jacobi)
        #pragma unroll
        for (int q = 0; q < 2; ++q) {
            const int m = tid + q * NTHR;
            if (m < nS) posS[m] = make_float2(px[q] - ax[q], py[q] - ay[q]);
        }
        __syncthreads();
    }
    // ---- section 0: final positions of own 8 i's ----
    if (tid < IPB)
        out[0 * NPART + blockIdx.x * IPB + tid] = posS[iloc[tid]];
}

extern "C" void kernel_launch(void* const* d_in, const int* in_sizes, int n_in,
                              void* d_out, int out_size, void* d_ws, size_t ws_size,
                              hipStream_t stream) {
    const float2* pos = (const float2*)d_in[0];
    const float2* ori = (const float2*)d_in[1];
    const float*  del = (const float*)d_in[2];
    const float*  rn  = (const float*)d_in[3];
    const float2* tn  = (const float2*)d_in[4];
    float2* o2 = (float2*)d_out;          // [5][N] float2
    (void)d_ws; (void)ws_size;

    fused_all<<<dim3(NBLK), dim3(NTHR), 0, stream>>>(pos, ori, del, rn, tn, o2);
}

// Round 13
// 88.498 us; speedup vs baseline: 1.0955x; 1.0955x over previous
//
#include <hip/hip_runtime.h>
#include <math.h>

#define NPART 4096
#define NBLK  512
#define NTHR  256
#define IPB   8     // particles (i) per block
#define SMAX  256   // local collision-set cap (expected ~110; own i's pre-seeded)
#define GDIM  64
#define NCELL (GDIM * GDIM)
#define PPT   (NPART / NTHR)   // 16 particles per thread

// Constants, rounded exactly as the reference's weak-typed doubles -> f32
constexpr float RORC   = (float)(2.5e-5 + 3.15e-6);    // RO + RC
constexpr float RORC2  = RORC * RORC;
constexpr float RRF    = 8e-6f;
constexpr float RR2    = RRF * RRF;
constexpr float TWORC  = (float)(2.0 * 3.15e-6);
constexpr float TWORC2 = TWORC * TWORC;
constexpr float C21RC  = (float)(2.1 * 3.15e-6);
constexpr float RCAND2 = 1.6e-9f;                      // (4e-5)^2 >= 3-hop chain span
constexpr float GMIN   = -2.048e-3f;
constexpr float GINV   = 15625.0f;                     // 1 / 6.4e-5
constexpr float C_ROT  = (float)(0.2 * 25.0 * 0.0028);
constexpr float C_RN1  = (float)0.07483314773547883;
constexpr float C_SQDT = (float)0.4472135954999579;
constexpr float C_TRV  = (float)(0.2 * 5e-7);
constexpr float C_HALF = (float)0.7071067811865476;
constexpr float C_SQ2T = (float)1.6733200530681511e-07;
constexpr float EPSF   = 1e-14f;

__device__ __forceinline__ int cell_of(float x, float y) {
    int cx = (int)floorf((x - GMIN) * GINV);
    int cy = (int)floorf((y - GMIN) * GINV);
    cx = min(max(cx, 0), GDIM - 1);
    cy = min(max(cy, 0), GDIM - 1);
    return cy * GDIM + cx;
}

// ---------------------------------------------------------------------------
// ONE kernel, 512 blocks x 256 thr. vs R12: LDS trimmed 69.3 -> ~61.7 KB to
// test the occupancy-cliff hypothesis (>64KB LDS => 1 block/CU => two
// sequential block-waves; Occupancy 13.9% in R10/R12 vs 23.7% under R2's
// cooperative launch). Positions live in regs (pp[16]) + cell-sorted copy;
// phase-A reduction via 32-lane shuffles; own i's pre-seeded into S.
// ---------------------------------------------------------------------------
__global__ __launch_bounds__(NTHR) void fused_all(
        const float2* __restrict__ pos, const float2* __restrict__ ori,
        const float* __restrict__ Deltas, const float* __restrict__ rot_noise,
        const float2* __restrict__ trans_noise, float2* __restrict__ out) {
    __shared__ int      ptr[NCELL];           // 16 KB counts->starts->ends
    __shared__ unsigned short sortid[NPART];  // 8 KB
    __shared__ float4   sortpos4[NPART / 2];  // 32 KB cell-sorted positions
    __shared__ float    sred[2 * NTHR];       // 2 KB scan / mean
    __shared__ float    res[5][IPB];
    __shared__ unsigned bmap[NPART / 32];     // 512 B
    __shared__ int      Sidx[SMAX];           // 1 KB
    __shared__ float4   posS4[SMAX / 2];      // 2 KB
    __shared__ int      scnt;
    float2* sortpos = (float2*)sortpos4;
    float2* posS    = (float2*)posS4;
    int*    sredi   = (int*)sred;

    const int tid  = threadIdx.x;
    const int il   = tid >> 5;            // own-i 0..7
    const int lane = tid & 31;
    const int gi   = blockIdx.x * IPB + il;

    if (tid == 0) scnt = IPB;             // slots 0..7 = own i's
    if (tid < IPB) Sidx[tid] = blockIdx.x * IPB + tid;
    if (tid < NPART / 32) bmap[tid] = 0u;
    for (int k = 0; k < NCELL / NTHR; ++k)
        ptr[k * NTHR + tid] = 0;

    // ---- G1. positions -> registers; histogram ----
    float2 pp[PPT];
    int    cc[PPT];
    #pragma unroll
    for (int k = 0; k < PPT; ++k)
        pp[k] = pos[k * NTHR + tid];
    __syncthreads();                      // ptr zeroed
    #pragma unroll
    for (int k = 0; k < PPT; ++k) {
        cc[k] = cell_of(pp[k].x, pp[k].y);
        atomicAdd(&ptr[cc[k]], 1);
    }
    __syncthreads();

    // ---- G2. exclusive scan of 4096 counts ----
    {
        const int base = tid * (NCELL / NTHR);
        int v[NCELL / NTHR];
        int sum = 0;
        #pragma unroll
        for (int t = 0; t < NCELL / NTHR; ++t) { v[t] = ptr[base + t]; sum += v[t]; }
        sredi[tid] = sum;
        __syncthreads();
        for (int off = 1; off < NTHR; off <<= 1) {
            const int a = (tid >= off) ? sredi[tid - off] : 0;
            __syncthreads();
            sredi[tid] += a;
            __syncthreads();
        }
        int run = sredi[tid] - sum;
        #pragma unroll
        for (int t = 0; t < NCELL / NTHR; ++t) { ptr[base + t] = run; run += v[t]; }
    }
    __syncthreads();

    // ---- G3. scatter ids + positions (ptr becomes END offsets) ----
    #pragma unroll
    for (int k = 0; k < PPT; ++k) {
        const int slot = atomicAdd(&ptr[cc[k]], 1);
        sortid[slot]  = (unsigned short)(k * NTHR + tid);
        sortpos[slot] = pp[k];
    }
    __syncthreads();

    // ---- A. 3-row neighborhood sweep, 32 lanes per own-i ----
    const float2 pi = pos[gi];
    float nr = 0.f, sx = 0.f, sy = 0.f, oxs = 0.f, oys = 0.f;
    {
        int cxi = min(max((int)floorf((pi.x - GMIN) * GINV), 0), GDIM - 1);
        int cyi = min(max((int)floorf((pi.y - GMIN) * GINV), 0), GDIM - 1);
        for (int dyr = -1; dyr <= 1; ++dyr) {
            const int cy = cyi + dyr;
            if (cy < 0 || cy >= GDIM) continue;
            const int c_lo = cy * GDIM + max(cxi - 1, 0);
            const int c_hi = cy * GDIM + min(cxi + 1, GDIM - 1);
            const int b0 = (c_lo > 0) ? ptr[c_lo - 1] : 0;
            const int e0 = ptr[c_hi];
            for (int t = b0 + lane; t < e0; t += 32) {
                const float2 pj = sortpos[t];
                const float dxp = pj.x - pi.x, dyp = pj.y - pi.y;
                const float r2 = fmaf(dxp, dxp, dyp * dyp);
                if (r2 <= RCAND2) {       // incl. diagonal
                    const int j = sortid[t];
                    atomicOr(&bmap[j >> 5], 1u << (j & 31));
                    if (r2 <= RORC2) {    // inside_Ro
                        const float2 uj = ori[j];
                        oxs += uj.x; oys += uj.y;
                        if (r2 <= RR2 && r2 > 0.f) {
                            // in_front fails <=> dot<=0 && cross>=0
                            const float dt_ = fmaf(dxp, uj.x, dyp * uj.y);
                            const float cr_ = fmaf(dyp, uj.x, -dxp * uj.y);
                            if (!((dt_ <= 0.f) && (cr_ >= 0.f))) {
                                nr += 1.f; sx += pj.x; sy += pj.y;
                            }
                        }
                    }
                }
            }
        }
    }
    {   // 32-lane shuffle reduction (lanes of an i are one half-wave)
        float vals[5] = {nr, sx, sy, oxs, oys};
        #pragma unroll
        for (int q = 0; q < 5; ++q)
            #pragma unroll
            for (int off = 16; off >= 1; off >>= 1)
                vals[q] += __shfl_down(vals[q], off, 32);
        if (lane == 0) {
            res[0][il] = vals[0]; res[1][il] = vals[1]; res[2][il] = vals[2];
            res[3][il] = vals[3]; res[4][il] = vals[4];
        }
    }
    __syncthreads();                      // bmap + res final

    // ---- B. S-compaction from bmap (own-block bits masked out) ----
    if (tid < NPART / 32) {
        unsigned bits = bmap[tid];
        if (tid == (int)(blockIdx.x >> 2))
            bits &= ~(0xFFu << ((blockIdx.x & 3) * 8));
        while (bits) {
            const int b = __ffs(bits) - 1;
            bits &= bits - 1;
            const int slot = atomicAdd(&scnt, 1);
            if (slot < SMAX) Sidx[slot] = tid * 32 + b;
        }
    }
    __syncthreads();
    const int nS = (scnt < SMAX) ? scnt : SMAX;

    // ---- D1. translate S members (reference-exact expression) ----
    if (tid < nS) {
        const int p = Sidx[tid];
        const float2 pq = pos[p];
        const float2 uu = ori[p];
        const float2 tn = trans_noise[p];
        posS[tid] = make_float2(
            pq.x + (C_TRV * uu.x + ((tn.x * C_HALF) * C_SQ2T) * C_SQDT),
            pq.y + (C_TRV * uu.y + ((tn.y * C_HALF) * C_SQ2T) * C_SQDT));
    }

    // ---- C. mean of all positions from registers (same order as R12) ----
    float mx = 0.f, my = 0.f;
    #pragma unroll
    for (int k = 0; k < PPT; ++k) { mx += pp[k].x; my += pp[k].y; }
    sred[tid] = mx; sred[NTHR + tid] = my;
    __syncthreads();
    for (int s = NTHR / 2; s > 0; s >>= 1) {
        if (tid < s) { sred[tid] += sred[tid + s]; sred[NTHR + tid] += sred[NTHR + tid + s]; }
        __syncthreads();
    }
    const float cmx = sred[0]    * (1.f / NPART);
    const float cmy = sred[NTHR] * (1.f / NPART);

    // ---- C2. per-i epilogue (8 threads; sections 1..4) ----
    if (tid < IPB) {
        const int g2 = blockIdx.x * IPB + tid;
        const float2 p = pos[g2];
        const float2 u = ori[g2];
        const float nrv = res[0][tid], sxv = res[1][tid], syv = res[2][tid];
        const float osx = res[3][tid], osy = res[4][tid];

        const float inv = 1.f / fmaxf(nrv, 1.f);
        const float sg  = (nrv > 0.f) ? 1.f : 0.f;
        const float Sx = sxv * inv - p.x * sg;
        const float Sy = syv * inv - p.y * sg;
        const float dxv = -Sx, dyv = -Sy;        // d = -S

        const float Psx = cmx - p.x;
        const float Psy = cmy - p.y;

        float sd, cd;
        sincosf(Deltas[0], &sd, &cd);
        const float Lx = Psx * cd - Psy * sd;    // Ps * exp(+i*Delta)
        const float Ly = Psx * sd + Psy * cd;
        const float Rx = Psx * cd + Psy * sd;    // Ps * exp(-i*Delta)
        const float Ry = Psy * cd - Psx * sd;

        const float no  = fmaxf(sqrtf(osx * osx + osy * osy + 1e-30f), EPSF);
        const float nl  = fmaxf(sqrtf(Lx * Lx + Ly * Ly + 1e-30f), EPSF);
        const float nrr = fmaxf(sqrtf(Rx * Rx + Ry * Ry + 1e-30f), EPSF);
        const float csl = (Lx * osx + Ly * osy) / (nl * no);
        const float csr = (Rx * osx + Ry * osy) / (nrr * no);
        const bool left = (csl >= csr);
        const float bx = left ? Lx : Rx;
        const float by = left ? Ly : Ry;

        float cx, cy;
        if (dxv != 0.f || dyv != 0.f)    { cx = dxv; cy = dyv; }
        else if (bx != 0.f || by != 0.f) { cx = bx;  cy = by;  }
        else                             { cx = 1.f; cy = 0.f; }

        const float dt_ = cx * u.x + cy * u.y;
        const float cr_ = cy * u.x - cx * u.y;
        const float sin_t = cr_ / sqrtf(dt_ * dt_ + cr_ * cr_);

        const float ang = C_ROT * sin_t + (rot_noise[g2] * C_RN1) * C_SQDT;
        float sa, ca;
        sincosf(ang, &sa, &ca);
        out[1 * NPART + g2] = make_float2(u.x * ca - u.y * sa,
                                          u.x * sa + u.y * ca);
        out[2 * NPART + g2] = make_float2(osx, osy);
        out[3 * NPART + g2] = make_float2(Lx, Ly);
        out[4 * NPART + g2] = make_float2(Rx, Ry);
    }
    __syncthreads();                      // posS complete

    // ---- D2. three local JACOBI passes over S (nS <= 256 == NTHR) ----
    for (int pass = 0; pass < 3; ++pass) {
        float px = 0.f, py = 0.f, ax = 0.f, ay = 0.f;
        const bool mv = (tid < nS);
        if (mv) { px = posS[tid].x; py = posS[tid].y; }
        int b = 0;
        for (; b + 4 <= nS; b += 4) {
            const float4 w0 = posS4[(b >> 1)];
            const float4 w1 = posS4[(b >> 1) + 1];
            const float bxs[4] = {w0.x, w0.z, w1.x, w1.z};
            const float bys[4] = {w0.y, w0.w, w1.y, w1.w};
            #pragma unroll
            for (int s = 0; s < 4; ++s) {
                if (mv) {
                    const float dx = bxs[s] - px, dy = bys[s] - py;
                    const float r2 = fmaf(dx, dx, dy * dy);
                    if (r2 <= TWORC2 && r2 > 0.f) {
                        const float ab = sqrtf(r2);
                        const float sc = (C21RC - ab) * 0.5f / ab;
                        ax = fmaf(dx, sc, ax);
                        ay = fmaf(dy, sc, ay);
                    }
                }
            }
        }
        for (; b < nS; ++b) {
            const float2 pb = posS[b];
            if (mv) {
                const float dx = pb.x - px, dy = pb.y - py;
                const float r2 = fmaf(dx, dx, dy * dy);
                if (r2 <= TWORC2 && r2 > 0.f) {
                    const float ab = sqrtf(r2);
                    const float sc = (C21RC - ab) * 0.5f / ab;
                    ax = fmaf(dx, sc, ax);
                    ay = fmaf(dy, sc, ay);
                }
            }
        }
        __syncthreads();                  // all reads done (Jacobi)
        if (mv) posS[tid] = make_float2(px - ax, py - ay);
        __syncthreads();
    }
    // ---- section 0: own 8 i's are slots 0..7 of S ----
    if (tid < IPB)
        out[0 * NPART + blockIdx.x * IPB + tid] = posS[tid];
}

extern "C" void kernel_launch(void* const* d_in, const int* in_sizes, int n_in,
                              void* d_out, int out_size, void* d_ws, size_t ws_size,
                              hipStream_t stream) {
    const float2* pos = (const float2*)d_in[0];
    const float2* ori = (const float2*)d_in[1];
    const float*  del = (const float*)d_in[2];
    const float*  rn  = (const float*)d_in[3];
    const float2* tn  = (const float2*)d_in[4];
    float2* o2 = (float2*)d_out;          // [5][N] float2
    (void)d_ws; (void)ws_size;

    fused_all<<<dim3(NBLK), dim3(NTHR), 0, stream>>>(pos, ori, del, rn, tn, o2);
}